// Round 3
// baseline (73056.201 us; speedup 1.0000x reference)
//
#include <hip/hip_runtime.h>

typedef __attribute__((ext_vector_type(4))) float f32x4;
typedef __attribute__((ext_vector_type(8))) short bf16x8;
typedef __attribute__((ext_vector_type(4))) short bf16x4;
typedef __attribute__((ext_vector_type(4))) int i4v;
typedef _Float16 f16;
typedef __attribute__((ext_vector_type(8))) _Float16 f16x8;
typedef __attribute__((ext_vector_type(4))) _Float16 f16x4;

#define DEV static __device__ __forceinline__

constexpr int NB = 128;
constexpr int NS = 256;
constexpr int NT = 256;
constexpr int NV = 512;
constexpr int NH = 512;
constexpr int BH = NB * NH;  // 65536
constexpr float NEGV = -1e9f;

DEV float bf2f(short u) {
  unsigned int i = ((unsigned int)(unsigned short)u) << 16;
  float f; __builtin_memcpy(&f, &i, 4); return f;
}
DEV short f2bf(float x) {
  unsigned int i; __builtin_memcpy(&i, &x, 4);
  i += 0x7fffu + ((i >> 16) & 1u);
  return (short)(i >> 16);
}
DEV int pk(float x) {
  short h = f2bf(x);
  short l = f2bf(x - bf2f(h));
  return ((int)(unsigned short)h << 16) | (int)(unsigned short)l;
}
DEV float upkf(int v) { return bf2f((short)(v >> 16)) + bf2f((short)(v & 0xffff)); }
DEV float sigm(float x) { return 1.0f / (1.0f + __expf(-x)); }
DEV float tanh_(float x) { return 1.0f - 2.0f / (__expf(2.0f * x) + 1.0f); }
DEV f32x4 mfma16(bf16x8 a, bf16x8 b, f32x4 c) {
  return __builtin_amdgcn_mfma_f32_16x16x32_bf16(a, b, c, 0, 0, 0);
}

// ---- agent-scope (L3-coherent, cache-bypassing) atomics for intra-kernel cross-WG data ----
DEV int aload_i(const int* p) { return __hip_atomic_load(p, __ATOMIC_RELAXED, __HIP_MEMORY_SCOPE_AGENT); }
DEV void astore_i(int* p, int v) { __hip_atomic_store(p, v, __ATOMIC_RELAXED, __HIP_MEMORY_SCOPE_AGENT); }
DEV unsigned long long aload_l(const unsigned long long* p) {
  return __hip_atomic_load(p, __ATOMIC_RELAXED, __HIP_MEMORY_SCOPE_AGENT);
}
DEV float aload_f(const float* p) { return __hip_atomic_load(p, __ATOMIC_RELAXED, __HIP_MEMORY_SCOPE_AGENT); }
DEV void astore_f(float* p, float v) { __hip_atomic_store(p, v, __ATOMIC_RELAXED, __HIP_MEMORY_SCOPE_AGENT); }

// monotonic-counter grid barrier (counter never reset)
DEV void gbar(int* ctr, int target) {
  asm volatile("s_waitcnt vmcnt(0) lgkmcnt(0)" ::: "memory");
  __syncthreads();
  if (threadIdx.x == 0) {
    __hip_atomic_fetch_add(ctr, 1, __ATOMIC_RELAXED, __HIP_MEMORY_SCOPE_AGENT);
    while (aload_i(ctr) < target) __builtin_amdgcn_s_sleep(2);
    asm volatile("" ::: "memory");
  }
  __syncthreads();
}

// ---- A-fragment builders ----
DEV void frag_zero(bf16x8& ah, bf16x8& al) {
  bf16x8 z = {0, 0, 0, 0, 0, 0, 0, 0};
  ah = z; al = z;
}
DEV void frag_f16(const f16* p, bf16x8& ah, bf16x8& al) {
  f16x8 v = *(const f16x8*)p;
#pragma unroll
  for (int j = 0; j < 8; ++j) {
    float f = (float)v[j];
    short h = f2bf(f); ah[j] = h; al[j] = f2bf(f - bf2f(h));
  }
}
DEV void frag_f32(const float* p, bf16x8& ah, bf16x8& al) {
  f32x4 v0 = *(const f32x4*)p, v1 = *(const f32x4*)(p + 4);
#pragma unroll
  for (int j = 0; j < 4; ++j) {
    short h0 = f2bf(v0[j]); ah[j] = h0; al[j] = f2bf(v0[j] - bf2f(h0));
    short h1 = f2bf(v1[j]); ah[4 + j] = h1; al[4 + j] = f2bf(v1[j] - bf2f(h1));
  }
}
DEV void frag_pka(const int* p, bf16x8& ah, bf16x8& al) {  // packed hi|lo via agent loads
#pragma unroll
  for (int jj = 0; jj < 4; ++jj) {
    unsigned long long u = aload_l((const unsigned long long*)p + jj);
    int va = (int)u, vb = (int)(u >> 32);
    ah[jj * 2] = (short)(va >> 16); al[jj * 2] = (short)(va & 0xffff);
    ah[jj * 2 + 1] = (short)(vb >> 16); al[jj * 2 + 1] = (short)(vb & 0xffff);
  }
}
DEV void frag_pk(const int* p, bf16x8& ah, bf16x8& al) {  // packed hi|lo, plain loads
  i4v a = *(const i4v*)p; i4v b = *(const i4v*)(p + 4);
#pragma unroll
  for (int j = 0; j < 4; ++j) {
    ah[j] = (short)(a[j] >> 16); al[j] = (short)(a[j] & 0xffff);
    ah[4 + j] = (short)(b[j] >> 16); al[4 + j] = (short)(b[j] & 0xffff);
  }
}
DEV void frag_ctx(const float* v0, const float* v1, float a0, float a1, bf16x8& ah, bf16x8& al) {
#pragma unroll
  for (int jj = 0; jj < 4; ++jj) {
    unsigned long long u0 = aload_l((const unsigned long long*)v0 + jj);
    unsigned long long u1 = aload_l((const unsigned long long*)v1 + jj);
    float f0a = __uint_as_float((unsigned)u0), f0b = __uint_as_float((unsigned)(u0 >> 32));
    float f1a = __uint_as_float((unsigned)u1), f1b = __uint_as_float((unsigned)(u1 >> 32));
    float ma = a0 * f0a + a1 * f1a, mb = a0 * f0b + a1 * f1b;
    short ha = f2bf(ma); ah[jj * 2] = ha; al[jj * 2] = f2bf(ma - bf2f(ha));
    short hb = f2bf(mb); ah[jj * 2 + 1] = hb; al[jj * 2 + 1] = f2bf(mb - bf2f(hb));
  }
}

// ---- LDS weight staging: fp32 [4g][16c][128k] tile -> hi/lo bf16 planes ----
// layout (shorts): buf*16384 + pl*8192 + g*2048 + kc*512 + (kk*16 + c)*8 + j
DEV void stage_w(short* sW, int buf, const float* __restrict__ w, long K,
                 int cb, int kbase, int tid) {
#pragma unroll
  for (int it = 0; it < 8; ++it) {
    int id = it * 256 + tid;  // 2048 groups of 4 elements
    int j4 = id & 1, c = (id >> 1) & 15, kk = (id >> 5) & 3, kc = (id >> 7) & 3, g = id >> 9;
    const float* src = w + (long)(g * 512 + cb + c) * K + kbase + kc * 32 + kk * 8 + j4 * 4;
    f32x4 v = *(const f32x4*)src;
    bf16x4 h, l;
#pragma unroll
    for (int j = 0; j < 4; ++j) { short hh = f2bf(v[j]); h[j] = hh; l[j] = f2bf(v[j] - bf2f(hh)); }
    int base = buf * 16384 + g * 2048 + kc * 512 + (kk * 16 + c) * 8 + j4 * 4;
    *(bf16x4*)(sW + base) = h;
    *(bf16x4*)(sW + base + 8192) = l;
  }
}
DEV void phase_mfma(const short* sW, int buf, int lane, const bf16x8* AH, const bf16x8* AL, f32x4* acc) {
  const short* base = sW + buf * 16384;
#pragma unroll
  for (int kc = 0; kc < 4; ++kc) {
#pragma unroll
    for (int g = 0; g < 4; ++g) {
      bf16x8 wh = *(const bf16x8*)(base + g * 2048 + kc * 512 + lane * 8);
      bf16x8 wl = *(const bf16x8*)(base + 8192 + g * 2048 + kc * 512 + lane * 8);
      acc[g] = mfma16(AH[kc], wh, acc[g]);
      acc[g] = mfma16(AL[kc], wh, acc[g]);
      acc[g] = mfma16(AH[kc], wl, acc[g]);
    }
  }
}

// ---- prep kernels ----
__global__ void k_init(float* hinit, int* ctr) {
  int i = blockIdx.x * 256 + threadIdx.x;
  if (i < 4 * BH) hinit[i] = 0.f;
  if (i < 16) ctr[i] = 0;
}
// Wq [1024][512] fp32 -> wqPk [512][1024] packed hi|lo (transposed)
__global__ void k_convT(const float* __restrict__ src, int* __restrict__ dst) {
  int i = blockIdx.x * 256 + threadIdx.x;  // 524288
  int n = i >> 10, k = i & 1023;
  dst[i] = pk(src[k * 512 + n]);
}
__global__ void k_bias(const float* bi0, const float* bh0, const float* bi1, const float* bh1,
                       const float* dbi0, const float* dbh0, const float* dbi1, const float* dbh1,
                       float* e0, float* e1, float* d0, float* d1) {
  int i = blockIdx.x * 256 + threadIdx.x;
  if (i < 4096) { e0[i] = bi0[i] + bh0[i]; e1[i] = bi1[i] + bh1[i]; }
  if (i < 2048) { d0[i] = dbi0[i] + dbh0[i]; d1[i] = dbi1[i] + dbh1[i]; }
}

// ---- bidirectional LSTM layer: 128 WGs = xcd(8) x [cc-sub(4) x dir(2) x rh(2)] ----
template <int LAYER>
__global__ __launch_bounds__(256, 2) void k_enc(
    const int* __restrict__ source, const float* __restrict__ emb,  // layer0 input
    const f16* __restrict__ y0in,                                    // layer1 input
    const float* __restrict__ Wih, const float* __restrict__ Whh,
    const float* __restrict__ bsum,
    int* __restrict__ hbuf, f16* __restrict__ yout,
    float* __restrict__ hinitL, int* ctr) {
  constexpr int EX = LAYER ? 1024 : 256;
  constexpr int PX = EX / 128, P = PX + 4;
  __shared__ short sW[32768];  // 64KB: 2 bufs x (hi+lo) x 16KB
  const int wg = blockIdx.x, tid = threadIdx.x, wv = tid >> 6, lane = tid & 63;
  const int xx = wg & 7, ii = wg >> 3;
  const int cc = xx * 4 + (ii & 3), dir = (ii >> 2) & 1, rh = (ii >> 3) & 1;
  const int cb = cc * 16, r0 = rh * 64 + wv * 16;
  const int l15 = lane & 15, klane = (lane >> 4) * 8;
  const float* wih = Wih + (long)dir * 2048 * EX;
  const float* whh = Whh + (long)dir * 2048 * 512;
  const float* bs = bsum + dir * 2048;
  int bc = 0;
  for (int q = 0; q < 8; ++q) {  // zero my slice of both h parities
    int e = q * 256 + tid;
    int par = e >> 10, rr = (e >> 4) & 63, c2 = e & 15;
    astore_i(&hbuf[(dir * 2 + par) * BH + (rh * 64 + rr) * NH + cb + c2], 0);
  }
  gbar(ctr, 128 * ++bc);
  f32x4 cst = {0.f, 0.f, 0.f, 0.f};
  const int arow = r0 + l15, col = cb + l15;
  for (int t = 0; t < NS; ++t) {
    const int tt = dir ? (NS - 1 - t) : t;
    int tok = 0;
    const float* er = nullptr;
    const f16* xr = nullptr;
    if (LAYER == 0) {
      tok = source[arow * NS + tt];
      er = emb + (long)tok * 256;
    } else {
      xr = y0in + ((long)tt * NB + arow) * 1024;
    }
    const int* hr = hbuf + (long)(dir * 2 + (t & 1)) * BH + arow * NH;
    f32x4 acc[4] = {{0,0,0,0},{0,0,0,0},{0,0,0,0},{0,0,0,0}};
    stage_w(sW, 0, wih, EX, cb, 0, tid);
    __syncthreads();
    for (int p = 0; p < P; ++p) {
      if (p + 1 < P) {
        if (p + 1 < PX) stage_w(sW, (p + 1) & 1, wih, EX, cb, (p + 1) * 128, tid);
        else stage_w(sW, (p + 1) & 1, whh, 512, cb, (p + 1 - PX) * 128, tid);
      }
      bf16x8 AH[4], AL[4];
#pragma unroll
      for (int kc = 0; kc < 4; ++kc) {
        int kb = p * 128 + kc * 32 + klane;
        if (p < PX) {
          if (LAYER == 0) { if (tok) frag_f32(er + kb, AH[kc], AL[kc]); else frag_zero(AH[kc], AL[kc]); }
          else frag_f16(xr + kb, AH[kc], AL[kc]);
        } else {
          frag_pka(hr + kb - EX, AH[kc], AL[kc]);
        }
      }
      phase_mfma(sW, p & 1, lane, AH, AL, acc);
      __syncthreads();
    }
#pragma unroll
    for (int r = 0; r < 4; ++r) {
      int row = r0 + ((lane >> 4) << 2) + r;
      float iv = sigm(acc[0][r] + bs[col]);
      float fv = sigm(acc[1][r] + bs[512 + col]);
      float gv = tanh_(acc[2][r] + bs[1024 + col]);
      float ov = sigm(acc[3][r] + bs[1536 + col]);
      float cv = fv * cst[r] + iv * gv; cst[r] = cv;
      float hv = ov * tanh_(cv);
      astore_i(&hbuf[(long)(dir * 2 + ((t + 1) & 1)) * BH + row * NH + col], pk(hv));
      if (LAYER == 0) yout[((long)tt * NB + row) * 1024 + dir * 512 + col] = (f16)hv;
      else           yout[((long)row * NS + tt) * 1024 + dir * 512 + col] = (f16)hv;
      if (t == NS - 1) {
        atomicAdd(&hinitL[row * NH + col], hv);
        atomicAdd(&hinitL[BH + row * NH + col], cv);
      }
    }
    gbar(ctr, 128 * ++bc);
  }
}

// aprime = eo @ Wq : M=32768 N=512 K=1024; f16 A, packed-transposed Wq, f16 out
__global__ __launch_bounds__(256) void k_gemm_ap(const f16* __restrict__ A,
    const int* __restrict__ WPk, f16* __restrict__ C) {
  const int mt = blockIdx.x & 511, nt = blockIdx.x >> 9;
  const int wv = threadIdx.x >> 6, lane = threadIdx.x & 63;
  const int l15 = lane & 15, klane = (lane >> 4) * 8;
  const int r0 = mt * 64 + wv * 16, n0 = nt * 64;
  f32x4 acc[4] = {{0,0,0,0},{0,0,0,0},{0,0,0,0},{0,0,0,0}};
  const f16* ar = A + (long)(r0 + l15) * 1024;
  for (int k = 0; k < 1024; k += 32) {
    bf16x8 ah, al; frag_f16(ar + k + klane, ah, al);
#pragma unroll
    for (int g = 0; g < 4; ++g) {
      bf16x8 wh, wl;
      frag_pk(WPk + (long)(n0 + g * 16 + l15) * 1024 + k + klane, wh, wl);
      acc[g] = mfma16(ah, wh, acc[g]);
      acc[g] = mfma16(al, wh, acc[g]);
      acc[g] = mfma16(ah, wl, acc[g]);
    }
  }
#pragma unroll
  for (int g = 0; g < 4; ++g)
#pragma unroll
    for (int r = 0; r < 4; ++r) {
      int m = r0 + ((lane >> 4) << 2) + r;
      C[(long)m * 512 + n0 + g * 16 + l15] = (f16)acc[g][r];
    }
}

__global__ void k_sbias(const f16* __restrict__ eo, const float* __restrict__ bq,
                        float* __restrict__ sb) {
  int row = blockIdx.x * 256 + threadIdx.x;
  const f16* p = eo + (long)row * 1024;
  float acc = 0.f;
  for (int k = 0; k < 1024; k += 8) {
    f16x8 v = *(const f16x8*)(p + k);
#pragma unroll
    for (int j = 0; j < 8; ++j) acc += (float)v[j] * bq[k + j];
  }
  sb[row] = acc;
}

// persistent decoder: 256 WGs; attention on all WGs as (b,sh); cells on WGs 0..63
__global__ __launch_bounds__(256) void k_dec(
    const int* __restrict__ dects, const float* __restrict__ emb,
    const int* __restrict__ source,
    const f16* __restrict__ aprime, const float* __restrict__ sbias,
    const f16* __restrict__ eo,
    const float* __restrict__ dW0ih, const float* __restrict__ dW0hh,
    const float* __restrict__ dW1ih, const float* __restrict__ dW1hh,
    const float* __restrict__ db0, const float* __restrict__ db1,
    const float* __restrict__ hinit,
    int* __restrict__ d0h, int* __restrict__ d1h,
    float* __restrict__ attscal, float* __restrict__ attv,
    short* __restrict__ d1a, int* ctr) {
  __shared__ short sW[32768];            // 64KB total; softmax arrays alias the front
  float* s_d1 = (float*)sW;              // 512
  float* s_scp = s_d1 + 512;             // 2*128
  float* s_red = s_scp + 256;            // 8
  float* s_w = s_red + 8;                // 128
  const int wg = blockIdx.x, tid = threadIdx.x, wv = tid >> 6, lane = tid & 63;
  const int l15 = lane & 15, klane = (lane >> 4) * 8;
  int bc = 0;
  {  // init parity-0 states from encoder-summed finals
    int idx = wg * 256 + tid;
    astore_i(&d0h[idx], pk(hinit[idx]));
    astore_i(&d1h[idx], pk(hinit[2 * BH + idx]));
  }
  const bool cw = (wg < 64);
  int r0 = 0, cb = 0;
  f32x4 c0 = {0,0,0,0}, c1 = {0,0,0,0};
  if (cw) {
    int xx = wg & 7, ii = wg >> 3;
    cb = (xx * 4 + (ii & 3)) * 16;
    r0 = (ii >> 2) * 64 + wv * 16;
#pragma unroll
    for (int r = 0; r < 4; ++r) {
      int row = r0 + ((lane >> 4) << 2) + r;
      c0[r] = hinit[BH + row * NH + cb + l15];
      c1[r] = hinit[3 * BH + row * NH + cb + l15];
    }
  }
  gbar(ctr, 256 * ++bc);
  const int b = wg >> 1, sh = wg & 1;
  const int arow = r0 + l15, col = cb + l15;
  for (int t = 0; t < NT; ++t) {
    const int cur = t & 1, nxt = cur ^ 1;
    // ---- P2: attention (scores = aprime . d1h + sbias, split over s halves) ----
    {
      unsigned long long u = aload_l((const unsigned long long*)(d1h + cur * BH + b * NH) + tid);
      s_d1[tid * 2] = upkf((int)u);
      s_d1[tid * 2 + 1] = upkf((int)(u >> 32));
      __syncthreads();
      {
        int pp = tid >> 7, sl = tid & 127;
        const f16* ap = aprime + (long)(b * NS + sh * 128 + sl) * 512 + pp * 256;
        const float* sd = s_d1 + pp * 256;
        float acc = 0.f;
        for (int k = 0; k < 256; k += 8) {
          f16x8 v = *(const f16x8*)(ap + k);
#pragma unroll
          for (int j = 0; j < 8; ++j) acc += (float)v[j] * sd[k + j];
        }
        s_scp[pp * 128 + sl] = acc;
      }
      __syncthreads();
      if (tid < 128) {
        int s = sh * 128 + tid;
        float sv = s_scp[tid] + s_scp[128 + tid];
        sv = (source[b * NS + s] != 0) ? (sv + sbias[b * NS + s]) : NEGV;
        s_scp[tid] = sv;
        float m = sv;
#pragma unroll
        for (int o = 32; o > 0; o >>= 1) m = fmaxf(m, __shfl_xor(m, o, 64));
        if (lane == 0) s_red[wv] = m;
      }
      __syncthreads();
      if (tid < 128) {
        float mc = fmaxf(s_red[0], s_red[1]);
        float pv = __expf(s_scp[tid] - mc);
        s_w[tid] = pv;
#pragma unroll
        for (int o = 32; o > 0; o >>= 1) pv += __shfl_xor(pv, o, 64);
        if (lane == 0) s_red[4 + wv] = pv;
      }
      __syncthreads();
      if (tid == 0) {
        astore_f(&attscal[(b * 2 + sh) * 2 + 0], fmaxf(s_red[0], s_red[1]));
        astore_f(&attscal[(b * 2 + sh) * 2 + 1], s_red[4] + s_red[5]);
      }
      {  // unnormalized partial context, 4 dims/thread
        int d0 = tid * 4;
        float a0 = 0.f, a1 = 0.f, a2 = 0.f, a3 = 0.f;
        const f16* bp = eo + (long)(b * NS + sh * 128) * 1024 + d0;
        for (int sl = 0; sl < 128; ++sl) {
          float w = s_w[sl];
          f16x4 v = *(const f16x4*)(bp + (long)sl * 1024);
          a0 += w * (float)v[0]; a1 += w * (float)v[1];
          a2 += w * (float)v[2]; a3 += w * (float)v[3];
        }
        float* op = attv + (long)(b * 2 + sh) * 1024 + d0;
        astore_f(op + 0, a0); astore_f(op + 1, a1);
        astore_f(op + 2, a2); astore_f(op + 3, a3);
      }
    }
    gbar(ctr, 256 * ++bc);
    // ---- P4: decoder cell 0 (x = [emb(256) | ctx(1024)], h) ----
    if (cw) {
      float m0 = aload_f(&attscal[(arow * 2 + 0) * 2 + 0]), q0 = aload_f(&attscal[(arow * 2 + 0) * 2 + 1]);
      float m1 = aload_f(&attscal[(arow * 2 + 1) * 2 + 0]), q1 = aload_f(&attscal[(arow * 2 + 1) * 2 + 1]);
      float mm = fmaxf(m0, m1);
      float e0 = __expf(m0 - mm), e1 = __expf(m1 - mm);
      float inv = 1.0f / (e0 * q0 + e1 * q1);
      float al0 = e0 * inv, al1 = e1 * inv;
      const float* av0 = attv + (long)(arow * 2 + 0) * 1024;
      const float* av1 = attv + (long)(arow * 2 + 1) * 1024;
      int tok = dects[arow * NT + t];
      const float* er = emb + (long)tok * 256;
      const int* h0r = d0h + (long)cur * BH + arow * NH;
      f32x4 acc[4] = {{0,0,0,0},{0,0,0,0},{0,0,0,0},{0,0,0,0}};
      stage_w(sW, 0, dW0ih, 1280, cb, 0, tid);
      __syncthreads();
      for (int p = 0; p < 14; ++p) {
        if (p + 1 < 14) {
          if (p + 1 < 10) stage_w(sW, (p + 1) & 1, dW0ih, 1280, cb, (p + 1) * 128, tid);
          else stage_w(sW, (p + 1) & 1, dW0hh, 512, cb, (p + 1 - 10) * 128, tid);
        }
        bf16x8 AH[4], AL[4];
#pragma unroll
        for (int kc = 0; kc < 4; ++kc) {
          int kb = p * 128 + kc * 32 + klane;
          if (p < 2) { if (tok) frag_f32(er + kb, AH[kc], AL[kc]); else frag_zero(AH[kc], AL[kc]); }
          else if (p < 10) frag_ctx(av0 + kb - 256, av1 + kb - 256, al0, al1, AH[kc], AL[kc]);
          else frag_pka(h0r + kb - 1280, AH[kc], AL[kc]);
        }
        phase_mfma(sW, p & 1, lane, AH, AL, acc);
        __syncthreads();
      }
#pragma unroll
      for (int r = 0; r < 4; ++r) {
        int row = r0 + ((lane >> 4) << 2) + r;
        float iv = sigm(acc[0][r] + db0[col]);
        float fv = sigm(acc[1][r] + db0[512 + col]);
        float gv = tanh_(acc[2][r] + db0[1024 + col]);
        float ov = sigm(acc[3][r] + db0[1536 + col]);
        float cv = fv * c0[r] + iv * gv; c0[r] = cv;
        astore_i(&d0h[(long)nxt * BH + row * NH + col], pk(ov * tanh_(cv)));
      }
    }
    gbar(ctr, 256 * ++bc);
    // ---- P5: decoder cell 1 ----
    if (cw) {
      const int* h0n = d0h + (long)nxt * BH + arow * NH;
      const int* h1c = d1h + (long)cur * BH + arow * NH;
      f32x4 acc[4] = {{0,0,0,0},{0,0,0,0},{0,0,0,0},{0,0,0,0}};
      stage_w(sW, 0, dW1ih, 512, cb, 0, tid);
      __syncthreads();
      for (int p = 0; p < 8; ++p) {
        if (p + 1 < 8) {
          if (p + 1 < 4) stage_w(sW, (p + 1) & 1, dW1ih, 512, cb, (p + 1) * 128, tid);
          else stage_w(sW, (p + 1) & 1, dW1hh, 512, cb, (p + 1 - 4) * 128, tid);
        }
        bf16x8 AH[4], AL[4];
#pragma unroll
        for (int kc = 0; kc < 4; ++kc) {
          int kb = p * 128 + kc * 32 + klane;
          if (p < 4) frag_pka(h0n + kb, AH[kc], AL[kc]);
          else frag_pka(h1c + kb - 512, AH[kc], AL[kc]);
        }
        phase_mfma(sW, p & 1, lane, AH, AL, acc);
        __syncthreads();
      }
#pragma unroll
      for (int r = 0; r < 4; ++r) {
        int row = r0 + ((lane >> 4) << 2) + r;
        float iv = sigm(acc[0][r] + db1[col]);
        float fv = sigm(acc[1][r] + db1[512 + col]);
        float gv = tanh_(acc[2][r] + db1[1024 + col]);
        float ov = sigm(acc[3][r] + db1[1536 + col]);
        float cv = fv * c1[r] + iv * gv; c1[r] = cv;
        float hv = ov * tanh_(cv);
        astore_i(&d1h[(long)nxt * BH + row * NH + col], pk(hv));
        d1a[((long)t * NB + row) * 512 + col] = f2bf(hv);
      }
    }
    gbar(ctr, 256 * ++bc);
  }
}

// logits [32768,512] = d1a(bf16) @ Wout^T(fp32->hi/lo) + bout, write transposed [B,T,V]
__global__ __launch_bounds__(256) void k_gemm_out(const short* __restrict__ A,
    const float* __restrict__ Wout, const float* __restrict__ bias, float* __restrict__ out) {
  const int mt = blockIdx.x & 511, nt = blockIdx.x >> 9;
  const int wv = threadIdx.x >> 6, lane = threadIdx.x & 63;
  const int l15 = lane & 15, klane = (lane >> 4) * 8;
  const int r0 = mt * 64 + wv * 16, n0 = nt * 64;
  f32x4 acc[4] = {{0,0,0,0},{0,0,0,0},{0,0,0,0},{0,0,0,0}};
  const short* ar = A + (long)(r0 + l15) * 512;
  for (int k = 0; k < 512; k += 32) {
    bf16x8 a = *(const bf16x8*)(ar + k + klane);
#pragma unroll
    for (int g = 0; g < 4; ++g) {
      bf16x8 wh, wl;
      frag_f32(Wout + (long)(n0 + g * 16 + l15) * 512 + k + klane, wh, wl);
      acc[g] = mfma16(a, wh, acc[g]);
      acc[g] = mfma16(a, wl, acc[g]);
    }
  }
#pragma unroll
  for (int g = 0; g < 4; ++g)
#pragma unroll
    for (int r = 0; r < 4; ++r) {
      int m = r0 + ((lane >> 4) << 2) + r;
      int tt = m >> 7, bb = m & 127;
      int n = n0 + g * 16 + l15;
      out[(long)bb * (NT * NV) + tt * NV + n] = acc[g][r] + bias[n];
    }
}

extern "C" void kernel_launch(void* const* d_in, const int* in_sizes, int n_in,
                              void* d_out, int out_size, void* d_ws, size_t ws_size,
                              hipStream_t stream) {
  char* basep = (char*)d_ws;
  size_t off = 0;
  auto alloc = [&](size_t bytes) -> void* {
    off = (off + 255) & ~(size_t)255;
    void* p = basep + off;
    off += bytes;
    return p;
  };
  int* ctr = (int*)alloc(64);
  float* hinit = (float*)alloc((size_t)4 * BH * 4);   // 1MB
  float* eb0 = (float*)alloc(4096 * 4);
  float* eb1 = (float*)alloc(4096 * 4);
  float* db0 = (float*)alloc(2048 * 4);
  float* db1 = (float*)alloc(2048 * 4);
  int* wqPk = (int*)alloc((size_t)512 * 1024 * 4);    // 2MB
  // shared 67.1MB region: y0 (f16) -> aprime (f16, first half) + d1a (bf16, second half)
  char* region = (char*)alloc((size_t)32768 * 1024 * 2);
  f16* y0 = (f16*)region;
  f16* aprime = (f16*)region;
  short* d1a = (short*)(region + (size_t)32768 * 512 * 2);
  int* hbufE = (int*)alloc((size_t)4 * BH * 4);       // 1MB
  int* d0h = (int*)alloc((size_t)2 * BH * 4);
  int* d1h = (int*)alloc((size_t)2 * BH * 4);
  float* sbias = (float*)alloc(32768 * 4);
  float* attscal = (float*)alloc(512 * 4);
  float* attv = (float*)alloc((size_t)256 * 1024 * 4);
  if (off > ws_size) return;  // needs ~73MB

  const int* source = (const int*)d_in[0];
  const int* dects = (const int*)d_in[1];
  const float* emb = (const float*)d_in[2];
  f16* eo = (f16*)d_out;  // 67.1MB, dead before k_gemm_out writes logits

  k_init<<<1024, 256, 0, stream>>>(hinit, ctr);
  k_convT<<<2048, 256, 0, stream>>>((const float*)d_in[19], wqPk);
  k_bias<<<16, 256, 0, stream>>>((const float*)d_in[5], (const float*)d_in[6],
                                 (const float*)d_in[9], (const float*)d_in[10],
                                 (const float*)d_in[13], (const float*)d_in[14],
                                 (const float*)d_in[17], (const float*)d_in[18],
                                 eb0, eb1, db0, db1);
  k_enc<0><<<128, 256, 0, stream>>>(source, emb, nullptr,
                                    (const float*)d_in[3], (const float*)d_in[4], eb0,
                                    hbufE, y0, hinit, ctr);
  k_enc<1><<<128, 256, 0, stream>>>(nullptr, nullptr, y0,
                                    (const float*)d_in[7], (const float*)d_in[8], eb1,
                                    hbufE, eo, hinit + 2 * BH, ctr + 1);
  k_gemm_ap<<<4096, 256, 0, stream>>>(eo, wqPk, aprime);
  k_sbias<<<128, 256, 0, stream>>>(eo, (const float*)d_in[20], sbias);
  k_dec<<<256, 256, 0, stream>>>(dects, emb, source, aprime, sbias, eo,
                                 (const float*)d_in[11], (const float*)d_in[12],
                                 (const float*)d_in[15], (const float*)d_in[16],
                                 db0, db1, hinit, d0h, d1h, attscal, attv, d1a, ctr + 2);
  k_gemm_out<<<4096, 256, 0, stream>>>(d1a, (const float*)d_in[21],
                                       (const float*)d_in[22], (float*)d_out);
}